// Round 1
// 87.106 us; speedup vs baseline: 1.0125x; 1.0125x over previous
//
#include <hip/hip_runtime.h>
#include <math.h>

// Problem constants (match reference)
#define N_CAM 2
#define PH 96
#define PW 144
#define NPTS 200
#define VD 32
#define VH 128
#define VW 384

constexpr float MIN_DEPTH = 1.0f;
constexpr float MAX_DEPTH = 4000.0f;
constexpr float EPS_T = 1e-10f;
constexpr float VOXEL = 2.5f;

#define SEG 8                       // lanes per ray
#define PIX_PER_BLOCK (256 / SEG)   // 32
#define TOTAL_PIX (N_CAM * PH * PW) // 27648
#define RENDER_BLOCKS (TOTAL_PIX / PIX_PER_BLOCK) // 864
#define BEV_BLOCKS ((VH * VW) / 256)              // 192
#define TOTAL_BLOCKS (RENDER_BLOCKS + BEV_BLOCKS) // 1056

// ws layout: 4 floats per block (3 partials + pad). Written unconditionally by
// every block -> no zero-init needed (ws is 0xAA-poisoned each call).
// Round 3 post-mortem: ~2900 same-address device atomicAdds cost ~35-40us of
// serialized cross-XCD service; per-block partial stores + tiny reduce instead.
// Round 2 post-mortem: per-block __threadfence() = L2 wb+inv on gfx950 -> 90us.
// This round (polish R0): the 8 per-corner bounds guards in the trilinear loop
// forced 8 exec-masked load+wait clusters per sample (8 serialized latency
// round-trips). Replaced with branchless clamp+zero-weight taps: all 32 loads
// issue in ONE cluster -> one vmcnt wait per sample. Exact fp tree and
// accumulation order preserved (invalid corners add fmaf(v,+0,d)=d exactly).
// Also: BEV blocks moved to the FRONT of the grid (their 192-block strided-
// load tail now overlaps the render ramp), and ray-box setup uses one
// reciprocal per axis instead of two divides (+-1 depth-step margin >> ulp).

__device__ __forceinline__ float huber01(float diff) {
    // (sqrt(1 + diff^2/0.01) - 1) * 0.1 ; always >= 0 so |.| is a no-op
    float t = diff * 10.0f;
    return (sqrtf(fmaf(t, t, 1.0f)) - 1.0f) * 0.1f;
}

__global__ __launch_bounds__(256) void work_kernel(
    const float* __restrict__ dens,      // [VD*VH*VW]
    const float* __restrict__ cols,      // [3*VD*VH*VW] planar
    const float* __restrict__ tsil,      // [N_CAM*PH*PW]
    const float* __restrict__ timg,      // [N_CAM*PH*PW*3]
    const float* __restrict__ focal,     // [N_CAM*2]
    const float* __restrict__ principal, // [N_CAM*2]
    const float* __restrict__ Rm,        // [N_CAM*9]
    const float* __restrict__ Tv,        // [N_CAM*3]
    float* __restrict__ ws)              // [TOTAL_BLOCKS*4] partials
{
    const int tid = threadIdx.x;
    float p0 = 0.f, p1 = 0.f, p2 = 0.f; // block partials (col, sil, bev)

    if (blockIdx.x >= BEV_BLOCKS) {
        // ---------------- render + losses ----------------
        const int rb  = blockIdx.x - BEV_BLOCKS;
        const int seg = tid & (SEG - 1);
        const int pix = rb * PIX_PER_BLOCK + (tid >> 3);

        const int n   = (pix >= PH * PW) ? 1 : 0; // N_CAM == 2
        const int rem = pix - n * (PH * PW);
        const int h   = rem / PW;
        const int w   = rem - h * PW;

        const float dx = ((float)w + 0.5f - principal[n * 2 + 0]) / focal[n * 2 + 0];
        const float dy = ((float)h + 0.5f - principal[n * 2 + 1]) / focal[n * 2 + 1];
        const float* R  = Rm + n * 9;
        const float* Tc = Tv + n * 3;
        const float dwx = R[0] * dx + R[1] * dy + R[2];
        const float dwy = R[3] * dx + R[4] * dy + R[5];
        const float dwz = R[6] * dx + R[7] * dy + R[8];
        const float ox = -(Tc[0] * R[0] + Tc[1] * R[1] + Tc[2] * R[2]);
        const float oy = -(Tc[0] * R[3] + Tc[1] * R[4] + Tc[2] * R[5]);
        const float oz = -(Tc[0] * R[6] + Tc[1] * R[7] + Tc[2] * R[8]);

        const float inv_vox = 1.0f / VOXEL;
        const float bx = (VW - 1) * 0.5f;
        const float by = (VH - 1) * 0.5f;
        const float bz = (VD - 1) * 0.5f;
        const float dstep = (MAX_DEPTH - MIN_DEPTH) / (float)(NPTS - 1);

        // Analytic ray-box clamp in grid space: g_axis(t) in (-1, DIM).
        // Outside samples contribute exactly d=0 -> A,P *= 1.0f exactly in fp32.
        // Per-sample in-box guard below is authoritative; +-1-step margins on
        // k0/k1 absorb the reciprocal's ulp-level rounding (error ~1e-4 << 20).
        float tn = MIN_DEPTH, tf = MAX_DEPTH;
        {
            const float o3[3] = {ox, oy, oz};
            const float d3[3] = {dwx, dwy, dwz};
            const float b3[3] = {bx, by, bz};
            const float m3[3] = {(float)VW, (float)VH, (float)VD};
            #pragma unroll
            for (int ax = 0; ax < 3; ++ax) {
                const float o = o3[ax], dw = d3[ax], b = b3[ax], dim = m3[ax];
                if (fabsf(dw) > 1e-12f) {
                    const float invd = 1.0f / dw;
                    const float ta = (((-1.0f - b) * VOXEL) - o) * invd;
                    const float tb = (((dim  - b) * VOXEL) - o) * invd;
                    tn = fmaxf(tn, fminf(ta, tb));
                    tf = fminf(tf, fmaxf(ta, tb));
                } else {
                    const float g = o * inv_vox + b;
                    if (!(g > -1.0f && g < dim)) { tn = 1.0f; tf = 0.0f; }
                }
            }
        }
        int k0 = (int)ceilf((tn - MIN_DEPTH) / dstep) - 1;  // -1 margin
        int k1 = (int)floorf((tf - MIN_DEPTH) / dstep) + 2; // exclusive, +1 margin
        k0 = max(k0, 0);
        k1 = min(k1, NPTS);
        if (k1 < k0) k1 = k0;
        const int len = k1 - k0;
        const int L = (len + SEG - 1) / SEG; // contiguous chunk per lane
        const int s0 = k0 + seg * L;
        const int s1 = min(k1, s0 + L);

        float F0 = 0.f, F1 = 0.f, F2 = 0.f;
        float A = 1.0f, P = 1.0f;
        const int S = VD * VH * VW;
        const float* __restrict__ colR = cols;
        const float* __restrict__ colG = cols + S;
        const float* __restrict__ colB = cols + 2 * S;

        for (int k = s0; k < s1; ++k) {
            const float depth = fmaf((float)k, dstep, MIN_DEPTH);
            const float gx = fmaf(fmaf(depth, dwx, ox), inv_vox, bx);
            const float gy = fmaf(fmaf(depth, dwy, oy), inv_vox, by);
            const float gz = fmaf(fmaf(depth, dwz, oz), inv_vox, bz);

            float d = 0.f, r = 0.f, g = 0.f, b = 0.f;
            if (gx > -1.f && gx < (float)VW &&
                gy > -1.f && gy < (float)VH &&
                gz > -1.f && gz < (float)VD) {
                const float x0f = floorf(gx), y0f = floorf(gy), z0f = floorf(gz);
                const float fx = gx - x0f, fy = gy - y0f, fz = gz - z0f;
                const int x0 = (int)x0f, y0 = (int)y0f, z0 = (int)z0f;

                // Branchless: clamped (always-safe) indices; validity folded
                // into per-axis weights. Invalid corner => weight exactly +0.
                const int xa = max(x0, 0),     xb = min(x0 + 1, VW - 1);
                const int ya = max(y0, 0),     yb = min(y0 + 1, VH - 1);
                const int za = max(z0, 0),     zb = min(z0 + 1, VD - 1);
                const float wxa = (x0 >= 0)     ? 1.0f - fx : 0.0f;
                const float wxb = (x0 + 1 < VW) ? fx        : 0.0f;
                const float wya = (y0 >= 0)     ? 1.0f - fy : 0.0f;
                const float wyb = (y0 + 1 < VH) ? fy        : 0.0f;
                const float wza = (z0 >= 0)     ? 1.0f - fz : 0.0f;
                const float wzb = (z0 + 1 < VD) ? fz        : 0.0f;

                // Same multiply tree as reference: (wx*wy)*wz
                const float q00 = wxa * wya, q10 = wxb * wya;
                const float q01 = wxa * wyb, q11 = wxb * wyb;
                const float wt0 = q00 * wza, wt1 = q10 * wza;
                const float wt2 = q01 * wza, wt3 = q11 * wza;
                const float wt4 = q00 * wzb, wt5 = q10 * wzb;
                const float wt6 = q01 * wzb, wt7 = q11 * wzb;

                const int rowaa = (za * VH + ya) * VW;
                const int rowab = (za * VH + yb) * VW;
                const int rowba = (zb * VH + ya) * VW;
                const int rowbb = (zb * VH + yb) * VW;
                const int i0 = rowaa + xa, i1 = rowaa + xb;
                const int i2 = rowab + xa, i3 = rowab + xb;
                const int i4 = rowba + xa, i5 = rowba + xb;
                const int i6 = rowbb + xa, i7 = rowbb + xb;

                // All 32 loads unguarded -> single issue cluster, one wait.
                const float vd0 = dens[i0], vd1 = dens[i1], vd2 = dens[i2], vd3 = dens[i3];
                const float vd4 = dens[i4], vd5 = dens[i5], vd6 = dens[i6], vd7 = dens[i7];
                const float vr0 = colR[i0], vr1 = colR[i1], vr2 = colR[i2], vr3 = colR[i3];
                const float vr4 = colR[i4], vr5 = colR[i5], vr6 = colR[i6], vr7 = colR[i7];
                const float vg0 = colG[i0], vg1 = colG[i1], vg2 = colG[i2], vg3 = colG[i3];
                const float vg4 = colG[i4], vg5 = colG[i5], vg6 = colG[i6], vg7 = colG[i7];
                const float vb0 = colB[i0], vb1 = colB[i1], vb2 = colB[i2], vb3 = colB[i3];
                const float vb4 = colB[i4], vb5 = colB[i5], vb6 = colB[i6], vb7 = colB[i7];

                // Accumulation order identical to reference (c8 = 0..7).
                d = fmaf(vd0, wt0, d); r = fmaf(vr0, wt0, r); g = fmaf(vg0, wt0, g); b = fmaf(vb0, wt0, b);
                d = fmaf(vd1, wt1, d); r = fmaf(vr1, wt1, r); g = fmaf(vg1, wt1, g); b = fmaf(vb1, wt1, b);
                d = fmaf(vd2, wt2, d); r = fmaf(vr2, wt2, r); g = fmaf(vg2, wt2, g); b = fmaf(vb2, wt2, b);
                d = fmaf(vd3, wt3, d); r = fmaf(vr3, wt3, r); g = fmaf(vg3, wt3, g); b = fmaf(vb3, wt3, b);
                d = fmaf(vd4, wt4, d); r = fmaf(vr4, wt4, r); g = fmaf(vg4, wt4, g); b = fmaf(vb4, wt4, b);
                d = fmaf(vd5, wt5, d); r = fmaf(vr5, wt5, r); g = fmaf(vg5, wt5, g); b = fmaf(vb5, wt5, b);
                d = fmaf(vd6, wt6, d); r = fmaf(vr6, wt6, r); g = fmaf(vg6, wt6, g); b = fmaf(vb6, wt6, b);
                d = fmaf(vd7, wt7, d); r = fmaf(vr7, wt7, r); g = fmaf(vg7, wt7, g); b = fmaf(vb7, wt7, b);
            }
            const float wgt = d * A;
            F0 = fmaf(wgt, r, F0);
            F1 = fmaf(wgt, g, F1);
            F2 = fmaf(wgt, b, F2);
            A *= (1.0f + EPS_T - d);
            P *= (1.0f - d);
        }

        // Combine 8 contiguous segments (lanes) of this ray via shuffle scan.
        float incl = A;
        #pragma unroll
        for (int off = 1; off < SEG; off <<= 1) {
            float t = __shfl_up(incl, off, SEG);
            if (seg >= off) incl *= t;
        }
        float excl = __shfl_up(incl, 1, SEG);
        if (seg == 0) excl = 1.0f;

        float c0 = excl * F0, c1 = excl * F1, c2 = excl * F2;
        #pragma unroll
        for (int m = 1; m < SEG; m <<= 1) {
            c0 += __shfl_xor(c0, m, SEG);
            c1 += __shfl_xor(c1, m, SEG);
            c2 += __shfl_xor(c2, m, SEG);
            P  *= __shfl_xor(P, m, SEG);
        }

        float local_col = 0.f, local_sil = 0.f;
        if (seg == 0) {
            const float opac = 1.0f - P;
            local_sil = huber01(opac - tsil[pix]);
            const float* ti = timg + pix * 3;
            local_col = huber01(c0 - ti[0]) + huber01(c1 - ti[1]) + huber01(c2 - ti[2]);
        }

        #pragma unroll
        for (int m = 1; m < 64; m <<= 1) {
            local_col += __shfl_xor(local_col, m, 64);
            local_sil += __shfl_xor(local_sil, m, 64);
        }
        __shared__ float sc[4], ss[4];
        const int wave = tid >> 6;
        if ((tid & 63) == 0) { sc[wave] = local_col; ss[wave] = local_sil; }
        __syncthreads();
        p0 = sc[0] + sc[1] + sc[2] + sc[3];
        p1 = ss[0] + ss[1] + ss[2] + ss[3];
    } else {
        // ---------------- BEV loss (blocks 0..191: launched FIRST) ----------
        const int t = blockIdx.x * 256 + tid; // [0, VH*VW)
        // Two independent max chains: fmax is exactly associative, so this is
        // bit-identical while doubling load/compare ILP.
        float m0 = dens[t];
        float m1 = dens[(VH * VW) + t];
        #pragma unroll
        for (int z = 2; z < VD; z += 2) {
            m0 = fmaxf(m0, dens[z * (VH * VW) + t]);
            m1 = fmaxf(m1, dens[(z + 1) * (VH * VW) + t]);
        }
        float v = fabsf(fmaxf(m0, m1));
        #pragma unroll
        for (int msk = 1; msk < 64; msk <<= 1)
            v += __shfl_xor(v, msk, 64);
        __shared__ float sb[4];
        const int wave = tid >> 6;
        if ((tid & 63) == 0) sb[wave] = v;
        __syncthreads();
        p2 = sb[0] + sb[1] + sb[2] + sb[3];
    }

    // One plain 3-float store per block to a distinct slot. NO atomics.
    if (tid == 0) {
        float* slot = ws + (size_t)blockIdx.x * 4;
        slot[0] = p0;
        slot[1] = p1;
        slot[2] = p2;
    }
}

__global__ __launch_bounds__(256) void finalize_kernel(
    const float* __restrict__ ws, float* __restrict__ out)
{
    const int tid = threadIdx.x;
    float s0 = 0.f, s1 = 0.f, s2 = 0.f;
    for (int i = tid; i < TOTAL_BLOCKS; i += 256) {
        const float* slot = ws + (size_t)i * 4;
        s0 += slot[0];
        s1 += slot[1];
        s2 += slot[2];
    }
    #pragma unroll
    for (int m = 1; m < 64; m <<= 1) {
        s0 += __shfl_xor(s0, m, 64);
        s1 += __shfl_xor(s1, m, 64);
        s2 += __shfl_xor(s2, m, 64);
    }
    __shared__ float a0[4], a1[4], a2[4];
    const int wave = tid >> 6;
    if ((tid & 63) == 0) { a0[wave] = s0; a1[wave] = s1; a2[wave] = s2; }
    __syncthreads();
    if (tid == 0) {
        const float csum = a0[0] + a0[1] + a0[2] + a0[3];
        const float ssum = a1[0] + a1[1] + a1[2] + a1[3];
        const float bsum = a2[0] + a2[1] + a2[2] + a2[3];
        out[0] = csum / (float)(N_CAM * PH * PW * 3); // color_err
        out[1] = ssum / (float)(N_CAM * PH * PW);     // sil_err
        out[2] = bsum / (float)(VH * VW);             // bev_err
    }
}

extern "C" void kernel_launch(void* const* d_in, const int* in_sizes, int n_in,
                              void* d_out, int out_size, void* d_ws, size_t ws_size,
                              hipStream_t stream) {
    const float* dens      = (const float*)d_in[0];
    const float* cols      = (const float*)d_in[1];
    const float* tsil      = (const float*)d_in[2];
    const float* timg      = (const float*)d_in[3];
    const float* focal     = (const float*)d_in[4];
    const float* principal = (const float*)d_in[5];
    const float* Rm        = (const float*)d_in[6];
    const float* Tv        = (const float*)d_in[7];
    float* ws  = (float*)d_ws;
    float* out = (float*)d_out;

    // No memset: every ws slot used is written unconditionally by work_kernel.
    work_kernel<<<TOTAL_BLOCKS, 256, 0, stream>>>(
        dens, cols, tsil, timg, focal, principal, Rm, Tv, ws);
    finalize_kernel<<<1, 256, 0, stream>>>(ws, out);
}